// Round 5
// baseline (2240.104 us; speedup 1.0000x reference)
//
#include <hip/hip_runtime.h>

#define NN 20000      // nodes
#define NE 160000     // edges per edge set
#define NL 20         // EGNN layer calls (4*DEPTH)

typedef float f32x4 __attribute__((ext_vector_type(4)));
typedef __bf16 bf16x8 __attribute__((ext_vector_type(8)));

__device__ __forceinline__ float silu_f(float v) {
  return v / (1.f + __expf(-v));
}

// ---------------------------------------------------------------------------
// Pack fp32 weight matrix [L][K][128] into MFMA-B-fragment order:
// out[((layer*ktn + kt)*8 + nt)*64 + lane][8], elem j = W[kt*32+(lane>>4)*8+j][nt*16+(lane&15)]
// ---------------------------------------------------------------------------
__global__ void pack_weights(const float* __restrict__ W, __bf16* __restrict__ out,
                             const int K, const int lstride, const int total) {
  const int idx = blockIdx.x * 256 + threadIdx.x;
  if (idx >= total) return;
  const int lane = idx & 63;
  const int nt = (idx >> 6) & 7;
  const int ktn = K >> 5;
  const int kt = (idx >> 9) % ktn;
  const int layer = (idx >> 9) / ktn;
  const int col = nt * 16 + (lane & 15);
  const int kb = kt * 32 + (lane >> 4) * 8;
  const float* src = W + (size_t)layer * lstride;
  __bf16* o = out + (size_t)idx * 8;
#pragma unroll
  for (int j = 0; j < 8; ++j) o[j] = (__bf16)src[(kb + j) * 128 + col];
}

// ---------------------------------------------------------------------------
__global__ void embed_kernel(const float* __restrict__ x, const float* __restrict__ embW,
                             const float* __restrict__ embB,
                             float* __restrict__ h, float* __restrict__ h0,
                             __bf16* __restrict__ hbf) {
  const int idx = blockIdx.x * 256 + threadIdx.x;   // grid sized exactly NN*128/256
  const int n = idx >> 7, d = idx & 127;
  const float v = x[n] * embW[d] + embB[d];
  h[idx] = v;
  h0[idx] = v;
  hbf[idx] = (__bf16)v;
}

// ---------------------------------------------------------------------------
// CSR build: histogram of dst, exclusive scan, per-edge CSR slot (eperm).
// ---------------------------------------------------------------------------
__global__ void hist_kernel(const int* __restrict__ ei, int* __restrict__ deg) {
  const int e = blockIdx.x * 256 + threadIdx.x;   // grid exactly NE/256
  atomicAdd(&deg[ei[NE + e]], 1);
}

__global__ void scan_kernel(const int* __restrict__ deg, int* __restrict__ rowstart) {
  // one block (1024 thr) per edge set; exclusive scan of deg[r][0..NN)
  __shared__ int part[1024];
  const int r = blockIdx.x, t = threadIdx.x;
  const int* d = deg + (size_t)r * NN;
  int* rs = rowstart + (size_t)r * NN;
  int loc[20];
  int cnt = 0;
#pragma unroll
  for (int j = 0; j < 20; ++j) {
    const int i = t * 20 + j;
    const int v = (i < NN) ? d[i] : 0;
    loc[j] = cnt; cnt += v;
  }
  part[t] = cnt;
  __syncthreads();
  for (int off = 1; off < 1024; off <<= 1) {
    const int v = (t >= off) ? part[t - off] : 0;
    __syncthreads();
    part[t] += v;
    __syncthreads();
  }
  const int excl = (t == 0) ? 0 : part[t - 1];
#pragma unroll
  for (int j = 0; j < 20; ++j) {
    const int i = t * 20 + j;
    if (i < NN) rs[i] = excl + loc[j];
  }
}

__global__ void fill_kernel(const int* __restrict__ ei, const int* __restrict__ rowstart,
                            int* __restrict__ cursor, int* __restrict__ eperm) {
  const int e = blockIdx.x * 256 + threadIdx.x;
  const int d = ei[NE + e];
  const int p = atomicAdd(&cursor[d], 1);
  eperm[e] = rowstart[d] + p;   // CSR slot this edge's message will be stored at
}

// ---------------------------------------------------------------------------
// Fused edge-message kernel, weights-in-LDS version.
// Block = 1024 threads (16 waves). W1(64KB)+W2(32KB) staged to LDS once, then
// each wave independently processes 16 edges (full 16-row MFMAs):
//   GEMM1 (K=256, A gathered from global hbf, B via ds_read) -> LN -> SiLU ->
//   GEMM2 (K=128) -> LN -> SiLU -> message rows scattered to CSR slots.
// Dynamic LDS = 96KB weights + 16 x 4KB per-wave T1 = 160KB (1 block/CU).
// ---------------------------------------------------------------------------
__global__ __launch_bounds__(1024, 4) void edge_msg_kernel(
    const __bf16* __restrict__ hbf, const float* __restrict__ pos,
    const int* __restrict__ ei, const int* __restrict__ eperm, __bf16* __restrict__ msg,
    const __bf16* __restrict__ w1p, const __bf16* __restrict__ w2p,
    const float* __restrict__ w1last,
    const float* __restrict__ bm1, const float* __restrict__ gm1, const float* __restrict__ sm1,
    const float* __restrict__ bm2, const float* __restrict__ gm2, const float* __restrict__ sm2) {
  extern __shared__ char lds[];
  // stage packed weights (layer slice): W1 = 4096 uint4, W2 = 2048 uint4
  {
    const int t = threadIdx.x;
    uint4* d = (uint4*)lds;
    const uint4* s1 = (const uint4*)w1p;
#pragma unroll
    for (int j = 0; j < 4; ++j) d[t + j * 1024] = s1[t + j * 1024];
    const uint4* s2 = (const uint4*)w2p;
#pragma unroll
    for (int j = 0; j < 2; ++j) d[4096 + t + j * 1024] = s2[t + j * 1024];
  }
  __syncthreads();

  const int t = threadIdx.x, w = t >> 6, l = t & 63;
  const int lr = l & 15, lg = l >> 4;
  char* W1L = lds;                        // 64 KB
  char* W2L = lds + 65536;                // 32 KB
  char* T1  = lds + 98304 + w * 4096;     // 4 KB per wave

  const int e0 = blockIdx.x * 256 + w * 16;
  const int es = ei[e0 + lr], ed = ei[NE + e0 + lr];   // lane lr owns edge lr
  const int slotv = eperm[e0 + lr];
  const float dx = pos[ed * 3 + 0] - pos[es * 3 + 0];
  const float dy = pos[ed * 3 + 1] - pos[es * 3 + 1];
  const float dz = pos[ed * 3 + 2] - pos[es * 3 + 2];
  const float dist = sqrtf(dx * dx + dy * dy + dz * dz);

  // acc init = dist*Wm1[256] + bm1; C layout: row(edge) = lg*4+r, col = nt*16+lr
  f32x4 acc[8];
  {
    float drow[4];
#pragma unroll
    for (int r = 0; r < 4; ++r) drow[r] = __shfl(dist, lg * 4 + r);
#pragma unroll
    for (int nt = 0; nt < 8; ++nt) {
      const float wl = w1last[nt * 16 + lr], bb = bm1[nt * 16 + lr];
#pragma unroll
      for (int r = 0; r < 4; ++r) acc[nt][r] = drow[r] * wl + bb;
    }
  }
  // GEMM1: [16 x 256] @ [256 x 128]; A gathered from hbf, B from LDS
#pragma unroll
  for (int kt = 0; kt < 8; ++kt) {
    const int node = (kt < 4) ? ed : es;
    const bf16x8 a = *(const bf16x8*)(hbf + (size_t)node * 128 + (kt & 3) * 32 + lg * 8);
#pragma unroll
    for (int nt = 0; nt < 8; ++nt) {
      const bf16x8 b = *(const bf16x8*)(W1L + ((kt * 8 + nt) * 64 + l) * 16);
      acc[nt] = __builtin_amdgcn_mfma_f32_16x16x32_bf16(a, b, acc[nt], 0, 0, 0);
    }
  }
  // LN1 + SiLU -> T1
  {
    float g1c[8], s1c[8];
#pragma unroll
    for (int nt = 0; nt < 8; ++nt) { g1c[nt] = gm1[nt * 16 + lr]; s1c[nt] = sm1[nt * 16 + lr]; }
#pragma unroll
    for (int r = 0; r < 4; ++r) {
      float s = 0.f, q = 0.f;
#pragma unroll
      for (int nt = 0; nt < 8; ++nt) { const float v = acc[nt][r]; s += v; q += v * v; }
#pragma unroll
      for (int m = 1; m < 16; m <<= 1) { s += __shfl_xor(s, m); q += __shfl_xor(q, m); }
      const float mu = s * 0.0078125f;
      const float rstd = rsqrtf(q * 0.0078125f - mu * mu + 1e-5f);
      const int row = lg * 4 + r;
#pragma unroll
      for (int nt = 0; nt < 8; ++nt) {
        float v = (acc[nt][r] - mu) * rstd * g1c[nt] + s1c[nt];
        v = silu_f(v);
        *(__bf16*)(T1 + ((row * 256 + (nt * 16 + lr) * 2) ^ ((row & 7) << 4))) = (__bf16)v;
      }
    }
  }
  // GEMM2: [16 x 128] @ [128 x 128]
  f32x4 acc2[8];
#pragma unroll
  for (int nt = 0; nt < 8; ++nt) {
    const float bb = bm2[nt * 16 + lr];
#pragma unroll
    for (int r = 0; r < 4; ++r) acc2[nt][r] = bb;
  }
#pragma unroll
  for (int kt = 0; kt < 4; ++kt) {
    const bf16x8 a = *(const bf16x8*)(T1 + ((lr * 256 + kt * 64 + lg * 16) ^ ((lr & 7) << 4)));
#pragma unroll
    for (int nt = 0; nt < 8; ++nt) {
      const bf16x8 b = *(const bf16x8*)(W2L + ((kt * 8 + nt) * 64 + l) * 16);
      acc2[nt] = __builtin_amdgcn_mfma_f32_16x16x32_bf16(a, b, acc2[nt], 0, 0, 0);
    }
  }
  // LN2 + SiLU -> T1 (overwrite is safe: all GEMM2 reads precede in program order)
  {
    float g2c[8], s2c[8];
#pragma unroll
    for (int nt = 0; nt < 8; ++nt) { g2c[nt] = gm2[nt * 16 + lr]; s2c[nt] = sm2[nt * 16 + lr]; }
#pragma unroll
    for (int r = 0; r < 4; ++r) {
      float s = 0.f, q = 0.f;
#pragma unroll
      for (int nt = 0; nt < 8; ++nt) { const float v = acc2[nt][r]; s += v; q += v * v; }
#pragma unroll
      for (int m = 1; m < 16; m <<= 1) { s += __shfl_xor(s, m); q += __shfl_xor(q, m); }
      const float mu = s * 0.0078125f;
      const float rstd = rsqrtf(q * 0.0078125f - mu * mu + 1e-5f);
      const int row = lg * 4 + r;
#pragma unroll
      for (int nt = 0; nt < 8; ++nt) {
        float v = (acc2[nt][r] - mu) * rstd * g2c[nt] + s2c[nt];
        v = silu_f(v);
        *(__bf16*)(T1 + ((row * 256 + (nt * 16 + lr) * 2) ^ ((row & 7) << 4))) = (__bf16)v;
      }
    }
  }
  // scatter msg rows to CSR slots (256B rows, 128B-line aligned full-line writes)
#pragma unroll
  for (int j = 0; j < 4; ++j) {
    const int row = j * 4 + lg;
    const uint4 v = *(const uint4*)(T1 + ((row * 256 + lr * 16) ^ ((row & 7) << 4)));
    const int srow = __shfl(slotv, row);
    *(uint4*)((char*)msg + (size_t)srow * 256 + lr * 16) = v;
  }
}

// ---------------------------------------------------------------------------
// Fused CSR-gather aggregation + node-update MLP. 1 wave/block, 16 nodes/wave.
// Messages are stored in CSR order -> gather is a CONTIGUOUS streaming read of
// deg*256B per node (no indirection), unrolled 2 rows for ILP.
// ---------------------------------------------------------------------------
__global__ __launch_bounds__(64) void agg_update_kernel(
    float* __restrict__ h, __bf16* __restrict__ hbf, float* __restrict__ h0, const int mode,
    const __bf16* __restrict__ msg, const int* __restrict__ rowstart,
    const int* __restrict__ deg,
    const __bf16* __restrict__ w1p, const __bf16* __restrict__ w2p,
    const float* __restrict__ bu1, const float* __restrict__ gu1, const float* __restrict__ su1,
    const float* __restrict__ bu2, const float* __restrict__ gu2, const float* __restrict__ su2) {
  __shared__ __bf16 T1s[16 * 128];   // 4 KB
  char* T1 = (char*)T1s;
  const int l = threadIdx.x, lr = l & 15, lg = l >> 4;
  const int n0 = blockIdx.x * 16;
  const int n = n0 + lr;
  const int valid = (n < NN);

  // contiguous gather-sum of node n's message rows (4 lanes per node span the row)
  f32x4 agg[4][2];
#pragma unroll
  for (int kt = 0; kt < 4; ++kt) { agg[kt][0] = (f32x4)0.f; agg[kt][1] = (f32x4)0.f; }
  if (valid) {
    const int s = rowstart[n], dg = deg[n];
    const char* base = (const char*)msg + (size_t)s * 256 + lg * 16;
    int i = 0;
    for (; i + 2 <= dg; i += 2) {
      bf16x8 m0[4], m1[4];
#pragma unroll
      for (int kt = 0; kt < 4; ++kt) {
        m0[kt] = *(const bf16x8*)(base + (size_t)i * 256 + kt * 64);
        m1[kt] = *(const bf16x8*)(base + (size_t)(i + 1) * 256 + kt * 64);
      }
#pragma unroll
      for (int kt = 0; kt < 4; ++kt)
#pragma unroll
        for (int j = 0; j < 4; ++j) {
          agg[kt][0][j] += (float)m0[kt][j] + (float)m1[kt][j];
          agg[kt][1][j] += (float)m0[kt][j + 4] + (float)m1[kt][j + 4];
        }
    }
    if (i < dg) {
#pragma unroll
      for (int kt = 0; kt < 4; ++kt) {
        const bf16x8 mv = *(const bf16x8*)(base + (size_t)i * 256 + kt * 64);
#pragma unroll
        for (int j = 0; j < 4; ++j) {
          agg[kt][0][j] += (float)mv[j];
          agg[kt][1][j] += (float)mv[j + 4];
        }
      }
    }
  }
  // A fragments: kt 0..3 from hbf (coalesced rows), kt 4..7 from agg registers
  const int nc = valid ? n : 0;
  bf16x8 ah[4], af[4];
#pragma unroll
  for (int kt = 0; kt < 4; ++kt) {
    ah[kt] = *(const bf16x8*)(hbf + (size_t)nc * 128 + kt * 32 + lg * 8);
#pragma unroll
    for (int j = 0; j < 4; ++j) {
      af[kt][j] = (__bf16)agg[kt][0][j];
      af[kt][j + 4] = (__bf16)agg[kt][1][j];
    }
  }
  // GEMM1: [16 x 256] @ [256 x 128]
  f32x4 acc[8];
#pragma unroll
  for (int nt = 0; nt < 8; ++nt) {
    const float bb = bu1[nt * 16 + lr];
#pragma unroll
    for (int r = 0; r < 4; ++r) acc[nt][r] = bb;
  }
#pragma unroll
  for (int kt = 0; kt < 8; ++kt) {
    const bf16x8 a = (kt < 4) ? ah[kt] : af[kt - 4];
#pragma unroll
    for (int nt = 0; nt < 8; ++nt) {
      const bf16x8 b = *(const bf16x8*)(w1p + ((size_t)((kt * 8 + nt) * 64 + l)) * 8);
      acc[nt] = __builtin_amdgcn_mfma_f32_16x16x32_bf16(a, b, acc[nt], 0, 0, 0);
    }
  }
  // LN1 + SiLU -> T1
  {
    float g1c[8], s1c[8];
#pragma unroll
    for (int nt = 0; nt < 8; ++nt) { g1c[nt] = gu1[nt * 16 + lr]; s1c[nt] = su1[nt * 16 + lr]; }
#pragma unroll
    for (int r = 0; r < 4; ++r) {
      float s = 0.f, q = 0.f;
#pragma unroll
      for (int nt = 0; nt < 8; ++nt) { const float v = acc[nt][r]; s += v; q += v * v; }
#pragma unroll
      for (int m = 1; m < 16; m <<= 1) { s += __shfl_xor(s, m); q += __shfl_xor(q, m); }
      const float mu = s * 0.0078125f;
      const float rstd = rsqrtf(q * 0.0078125f - mu * mu + 1e-5f);
      const int row = lg * 4 + r;
#pragma unroll
      for (int nt = 0; nt < 8; ++nt) {
        float v = (acc[nt][r] - mu) * rstd * g1c[nt] + s1c[nt];
        v = silu_f(v);
        const int col = nt * 16 + lr;
        *(__bf16*)(T1 + ((row * 256 + col * 2) ^ ((row & 7) << 4))) = (__bf16)v;
      }
    }
  }
  // GEMM2: [16 x 128] @ [128 x 128]
  f32x4 acc2[8];
#pragma unroll
  for (int nt = 0; nt < 8; ++nt) {
    const float bb = bu2[nt * 16 + lr];
#pragma unroll
    for (int r = 0; r < 4; ++r) acc2[nt][r] = bb;
  }
#pragma unroll
  for (int kt = 0; kt < 4; ++kt) {
    const bf16x8 a = *(const bf16x8*)(T1 + ((lr * 256 + kt * 64 + lg * 16) ^ ((lr & 7) << 4)));
#pragma unroll
    for (int nt = 0; nt < 8; ++nt) {
      const bf16x8 b = *(const bf16x8*)(w2p + ((size_t)((kt * 8 + nt) * 64 + l)) * 8);
      acc2[nt] = __builtin_amdgcn_mfma_f32_16x16x32_bf16(a, b, acc2[nt], 0, 0, 0);
    }
  }
  // LN2 + SiLU + store h/hbf (+ residual, h0)
  {
    float g2c[8], s2c[8];
#pragma unroll
    for (int nt = 0; nt < 8; ++nt) { g2c[nt] = gu2[nt * 16 + lr]; s2c[nt] = su2[nt * 16 + lr]; }
#pragma unroll
    for (int r = 0; r < 4; ++r) {
      float s = 0.f, q = 0.f;
#pragma unroll
      for (int nt = 0; nt < 8; ++nt) { const float v = acc2[nt][r]; s += v; q += v * v; }
#pragma unroll
      for (int m = 1; m < 16; m <<= 1) { s += __shfl_xor(s, m); q += __shfl_xor(q, m); }
      const float mu = s * 0.0078125f;
      const float rstd = rsqrtf(q * 0.0078125f - mu * mu + 1e-5f);
      const int row = lg * 4 + r;
      const int nn = n0 + row;
      if (nn < NN) {
#pragma unroll
        for (int nt = 0; nt < 8; ++nt) {
          const int col = nt * 16 + lr;
          float v = (acc2[nt][r] - mu) * rstd * g2c[nt] + s2c[nt];
          v = silu_f(v);
          if (mode) v += h0[(size_t)nn * 128 + col];
          h[(size_t)nn * 128 + col] = v;
          hbf[(size_t)nn * 128 + col] = (__bf16)v;
          if (mode) h0[(size_t)nn * 128 + col] = v;
        }
      }
    }
  }
}

// ---------------------------------------------------------------------------
// Segmented pool: batch_ids are SORTED, so accumulate in registers and flush
// one atomic per bid-change (~20K atomics total instead of 2.56M).
// Block = 128 threads (one per dim), 256 nodes per block.
// ---------------------------------------------------------------------------
__global__ void pool_kernel(const float* __restrict__ h, const int* __restrict__ bid,
                            float* __restrict__ pooled) {
  const int d = threadIdx.x;                 // 128 threads
  const int n0 = blockIdx.x * 256;
  const int nend = (n0 + 256 < NN) ? (n0 + 256) : NN;
  float acc = 0.f;
  int cur = bid[n0];
  for (int n = n0; n < nend; ++n) {
    const int b = bid[n];                    // uniform across block -> broadcast
    if (b != cur) { atomicAdd(&pooled[cur * 128 + d], acc); acc = 0.f; cur = b; }
    acc += h[(size_t)n * 128 + d];
  }
  atomicAdd(&pooled[cur * 128 + d], acc);
}

__global__ void head_kernel(const float* __restrict__ pooled,
                            const float* __restrict__ W1, const float* __restrict__ b1,
                            const float* __restrict__ W2, const float* __restrict__ b2,
                            float* __restrict__ out) {
  __shared__ float buf[2];
  const int b = blockIdx.x, t = threadIdx.x;
  float s = b1[t];
  for (int k = 0; k < 128; ++k) s += pooled[b * 128 + k] * W1[k * 128 + t];
  s = fmaxf(s, 0.f) * W2[t];
#pragma unroll
  for (int m = 32; m >= 1; m >>= 1) s += __shfl_down(s, m);
  if ((t & 63) == 0) buf[t >> 6] = s;
  __syncthreads();
  if (t == 0) out[b] = buf[0] + buf[1] + b2[0];
}

// ---------------------------------------------------------------------------
extern "C" void kernel_launch(void* const* d_in, const int* in_sizes, int n_in,
                              void* d_out, int out_size, void* d_ws, size_t ws_size,
                              hipStream_t stream) {
  const float* x   = (const float*)d_in[0];
  const float* pos = (const float*)d_in[1];
  const int* eis[4] = {(const int*)d_in[2], (const int*)d_in[3],
                       (const int*)d_in[4], (const int*)d_in[5]};
  const int* bid = (const int*)d_in[6];
  const float* embW = (const float*)d_in[7];
  const float* embB = (const float*)d_in[8];
  const float* Wm1 = (const float*)d_in[9];
  const float* bm1 = (const float*)d_in[10];
  const float* gm1 = (const float*)d_in[11];
  const float* sm1 = (const float*)d_in[12];
  const float* Wm2 = (const float*)d_in[13];
  const float* bm2 = (const float*)d_in[14];
  const float* gm2 = (const float*)d_in[15];
  const float* sm2 = (const float*)d_in[16];
  const float* Wu1 = (const float*)d_in[17];
  const float* bu1 = (const float*)d_in[18];
  const float* gu1 = (const float*)d_in[19];
  const float* su1 = (const float*)d_in[20];
  const float* Wu2 = (const float*)d_in[21];
  const float* bu2 = (const float*)d_in[22];
  const float* gu2 = (const float*)d_in[23];
  const float* su2 = (const float*)d_in[24];
  const float* pW1 = (const float*)d_in[25];
  const float* pb1 = (const float*)d_in[26];
  const float* pW2 = (const float*)d_in[27];
  const float* pb2 = (const float*)d_in[28];
  float* out = (float*)d_out;

  char* wp = (char*)d_ws;
  float* h = (float*)wp;      wp += (size_t)NN * 128 * 4;
  float* h0 = (float*)wp;     wp += (size_t)NN * 128 * 4;
  float* pooled = (float*)wp; wp += 16 * 128 * 4;
  __bf16* hbf = (__bf16*)wp;  wp += (size_t)NN * 128 * 2;
  __bf16* msg = (__bf16*)wp;  wp += (size_t)NE * 128 * 2;   // 41 MB CSR-ordered messages
  __bf16* w1p = (__bf16*)wp;  wp += (size_t)NL * 32768 * 2;
  __bf16* w2p = (__bf16*)wp;  wp += (size_t)NL * 16384 * 2;
  __bf16* wu1p = (__bf16*)wp; wp += (size_t)NL * 32768 * 2;
  __bf16* wu2p = (__bf16*)wp; wp += (size_t)NL * 16384 * 2;
  int* deg = (int*)wp;        wp += (size_t)4 * NN * 4;
  int* cursor = (int*)wp;     wp += (size_t)4 * NN * 4;
  int* rowstart = (int*)wp;   wp += (size_t)4 * NN * 4;
  int* eperm = (int*)wp;      wp += (size_t)4 * NE * 4;

  // allow 160KB dynamic LDS for the edge kernel (host-side, capture-safe)
  static int lds_attr_set = 0;
  if (!lds_attr_set) {
    hipFuncSetAttribute((const void*)edge_msg_kernel,
                        hipFuncAttributeMaxDynamicSharedMemorySize, 163840);
    lds_attr_set = 1;
  }

  pack_weights<<<320, 256, 0, stream>>>(Wm1, w1p, 256, 257 * 128, NL * 8 * 8 * 64);
  pack_weights<<<160, 256, 0, stream>>>(Wm2, w2p, 128, 128 * 128, NL * 4 * 8 * 64);
  pack_weights<<<320, 256, 0, stream>>>(Wu1, wu1p, 256, 256 * 128, NL * 8 * 8 * 64);
  pack_weights<<<160, 256, 0, stream>>>(Wu2, wu2p, 128, 128 * 128, NL * 4 * 8 * 64);

  // CSR build (deg and cursor are adjacent -> one memset)
  hipMemsetAsync(deg, 0, (size_t)8 * NN * 4, stream);
  embed_kernel<<<(NN * 128) / 256, 256, 0, stream>>>(x, embW, embB, h, h0, hbf);
  for (int r = 0; r < 4; ++r)
    hist_kernel<<<NE / 256, 256, 0, stream>>>(eis[r], deg + (size_t)r * NN);
  scan_kernel<<<4, 1024, 0, stream>>>(deg, rowstart);
  for (int r = 0; r < 4; ++r)
    fill_kernel<<<NE / 256, 256, 0, stream>>>(eis[r], rowstart + (size_t)r * NN,
                                              cursor + (size_t)r * NN, eperm + (size_t)r * NE);

  for (int layer = 0; layer < 5; ++layer) {
    for (int r = 0; r < 4; ++r) {
      const int i = layer * 4 + r;
      edge_msg_kernel<<<NE / 256, 1024, 163840, stream>>>(
          hbf, pos, eis[r], eperm + (size_t)r * NE, msg,
          w1p + (size_t)i * 32768, w2p + (size_t)i * 16384,
          Wm1 + (size_t)i * 257 * 128 + 256 * 128,
          bm1 + i * 128, gm1 + i * 128, sm1 + i * 128,
          bm2 + i * 128, gm2 + i * 128, sm2 + i * 128);
      agg_update_kernel<<<(NN + 15) / 16, 64, 0, stream>>>(
          h, hbf, h0, (r == 3) ? 1 : 0,
          msg, rowstart + (size_t)r * NN, deg + (size_t)r * NN,
          wu1p + (size_t)i * 32768, wu2p + (size_t)i * 16384,
          bu1 + i * 128, gu1 + i * 128, su1 + i * 128,
          bu2 + i * 128, gu2 + i * 128, su2 + i * 128);
    }
  }

  hipMemsetAsync(pooled, 0, 16 * 128 * 4, stream);
  pool_kernel<<<(NN + 255) / 256, 128, 0, stream>>>(h, bid, pooled);
  head_kernel<<<16, 128, 0, stream>>>(pooled, pW1, pb1, pW2, pb2, out);
}

// Round 6
// 2058.625 us; speedup vs baseline: 1.0882x; 1.0882x over previous
//
#include <hip/hip_runtime.h>

#define NN 20000      // nodes
#define NE 160000     // edges per edge set
#define NL 20         // EGNN layer calls (4*DEPTH)

typedef float f32x4 __attribute__((ext_vector_type(4)));
typedef float f32x2 __attribute__((ext_vector_type(2)));
typedef __bf16 bf16x8 __attribute__((ext_vector_type(8)));

__device__ __forceinline__ float silu_f(float v) {
  return v / (1.f + __expf(-v));
}

// ---------------------------------------------------------------------------
// Pack fp32 weight matrix [L][K][128] into MFMA-B-fragment order:
// out[((layer*ktn + kt)*8 + nt)*64 + lane][8], elem j = W[kt*32+(lane>>4)*8+j][nt*16+(lane&15)]
// ---------------------------------------------------------------------------
__global__ void pack_weights(const float* __restrict__ W, __bf16* __restrict__ out,
                             const int K, const int lstride, const int total) {
  const int idx = blockIdx.x * 256 + threadIdx.x;
  if (idx >= total) return;
  const int lane = idx & 63;
  const int nt = (idx >> 6) & 7;
  const int ktn = K >> 5;
  const int kt = (idx >> 9) % ktn;
  const int layer = (idx >> 9) / ktn;
  const int col = nt * 16 + (lane & 15);
  const int kb = kt * 32 + (lane >> 4) * 8;
  const float* src = W + (size_t)layer * lstride;
  __bf16* o = out + (size_t)idx * 8;
#pragma unroll
  for (int j = 0; j < 8; ++j) o[j] = (__bf16)src[(kb + j) * 128 + col];
}

// ---------------------------------------------------------------------------
__global__ void embed_kernel(const float* __restrict__ x, const float* __restrict__ embW,
                             const float* __restrict__ embB,
                             float* __restrict__ h, float* __restrict__ h0,
                             __bf16* __restrict__ hbf) {
  const int idx = blockIdx.x * 256 + threadIdx.x;   // grid sized exactly NN*128/256
  const int n = idx >> 7, d = idx & 127;
  const float v = x[n] * embW[d] + embB[d];
  h[idx] = v;
  h0[idx] = v;
  hbf[idx] = (__bf16)v;
}

// ---------------------------------------------------------------------------
// CSR build: histogram of dst, exclusive scan, ordered edge list (eord).
// ---------------------------------------------------------------------------
__global__ void hist_kernel(const int* __restrict__ ei, int* __restrict__ deg) {
  const int e = blockIdx.x * 256 + threadIdx.x;   // grid exactly NE/256
  atomicAdd(&deg[ei[NE + e]], 1);
}

__global__ void scan_kernel(const int* __restrict__ deg, int* __restrict__ rowstart) {
  // one block (1024 thr) per edge set; exclusive scan of deg[r][0..NN)
  __shared__ int part[1024];
  const int r = blockIdx.x, t = threadIdx.x;
  const int* d = deg + (size_t)r * NN;
  int* rs = rowstart + (size_t)r * NN;
  int loc[20];
  int cnt = 0;
#pragma unroll
  for (int j = 0; j < 20; ++j) {
    const int i = t * 20 + j;
    const int v = (i < NN) ? d[i] : 0;
    loc[j] = cnt; cnt += v;
  }
  part[t] = cnt;
  __syncthreads();
  for (int off = 1; off < 1024; off <<= 1) {
    const int v = (t >= off) ? part[t - off] : 0;
    __syncthreads();
    part[t] += v;
    __syncthreads();
  }
  const int excl = (t == 0) ? 0 : part[t - 1];
#pragma unroll
  for (int j = 0; j < 20; ++j) {
    const int i = t * 20 + j;
    if (i < NN) rs[i] = excl + loc[j];
  }
}

__global__ void fill_kernel(const int* __restrict__ ei, const int* __restrict__ rowstart,
                            int* __restrict__ cursor, int* __restrict__ eord) {
  const int e = blockIdx.x * 256 + threadIdx.x;
  const int d = ei[NE + e];
  const int p = atomicAdd(&cursor[d], 1);
  eord[rowstart[d] + p] = e;
}

// ---------------------------------------------------------------------------
// Fused edge-message kernel, weights-in-LDS (R4-proven structure).
// Block = 1024 threads (16 waves); W1+W2 staged once; each wave owns 16 edges.
// Messages stored in EDGE order with fully contiguous 1KB wave stores.
// ---------------------------------------------------------------------------
__global__ __launch_bounds__(1024, 4) void edge_msg_kernel(
    const __bf16* __restrict__ hbf, const float* __restrict__ pos,
    const int* __restrict__ ei, __bf16* __restrict__ msg,
    const __bf16* __restrict__ w1p, const __bf16* __restrict__ w2p,
    const float* __restrict__ w1last,
    const float* __restrict__ bm1, const float* __restrict__ gm1, const float* __restrict__ sm1,
    const float* __restrict__ bm2, const float* __restrict__ gm2, const float* __restrict__ sm2) {
  extern __shared__ char lds[];
  // stage packed weights (layer slice): W1 = 4096 uint4, W2 = 2048 uint4
  {
    const int t = threadIdx.x;
    uint4* d = (uint4*)lds;
    const uint4* s1 = (const uint4*)w1p;
#pragma unroll
    for (int j = 0; j < 4; ++j) d[t + j * 1024] = s1[t + j * 1024];
    const uint4* s2 = (const uint4*)w2p;
#pragma unroll
    for (int j = 0; j < 2; ++j) d[4096 + t + j * 1024] = s2[t + j * 1024];
  }
  __syncthreads();

  const int t = threadIdx.x, w = t >> 6, l = t & 63;
  const int lr = l & 15, lg = l >> 4;
  char* W1L = lds;                        // 64 KB
  char* W2L = lds + 65536;                // 32 KB
  char* T1  = lds + 98304 + w * 4096;     // 4 KB per wave

  const int e0 = blockIdx.x * 256 + w * 16;
  const int es = ei[e0 + lr], ed = ei[NE + e0 + lr];   // lane lr owns edge lr
  const float dx = pos[ed * 3 + 0] - pos[es * 3 + 0];
  const float dy = pos[ed * 3 + 1] - pos[es * 3 + 1];
  const float dz = pos[ed * 3 + 2] - pos[es * 3 + 2];
  const float dist = sqrtf(dx * dx + dy * dy + dz * dz);

  // acc init = dist*Wm1[256] + bm1; C layout: row(edge) = lg*4+r, col = nt*16+lr
  f32x4 acc[8];
  {
    float drow[4];
#pragma unroll
    for (int r = 0; r < 4; ++r) drow[r] = __shfl(dist, lg * 4 + r);
#pragma unroll
    for (int nt = 0; nt < 8; ++nt) {
      const float wl = w1last[nt * 16 + lr], bb = bm1[nt * 16 + lr];
#pragma unroll
      for (int r = 0; r < 4; ++r) acc[nt][r] = drow[r] * wl + bb;
    }
  }
  // GEMM1: [16 x 256] @ [256 x 128]; A gathered from hbf, B from LDS
#pragma unroll
  for (int kt = 0; kt < 8; ++kt) {
    const int node = (kt < 4) ? ed : es;
    const bf16x8 a = *(const bf16x8*)(hbf + (size_t)node * 128 + (kt & 3) * 32 + lg * 8);
#pragma unroll
    for (int nt = 0; nt < 8; ++nt) {
      const bf16x8 b = *(const bf16x8*)(W1L + ((kt * 8 + nt) * 64 + l) * 16);
      acc[nt] = __builtin_amdgcn_mfma_f32_16x16x32_bf16(a, b, acc[nt], 0, 0, 0);
    }
  }
  // LN1 + SiLU -> T1
  {
    float g1c[8], s1c[8];
#pragma unroll
    for (int nt = 0; nt < 8; ++nt) { g1c[nt] = gm1[nt * 16 + lr]; s1c[nt] = sm1[nt * 16 + lr]; }
#pragma unroll
    for (int r = 0; r < 4; ++r) {
      float s = 0.f, q = 0.f;
#pragma unroll
      for (int nt = 0; nt < 8; ++nt) { const float v = acc[nt][r]; s += v; q += v * v; }
#pragma unroll
      for (int m = 1; m < 16; m <<= 1) { s += __shfl_xor(s, m); q += __shfl_xor(q, m); }
      const float mu = s * 0.0078125f;
      const float rstd = rsqrtf(q * 0.0078125f - mu * mu + 1e-5f);
      const int row = lg * 4 + r;
#pragma unroll
      for (int nt = 0; nt < 8; ++nt) {
        float v = (acc[nt][r] - mu) * rstd * g1c[nt] + s1c[nt];
        v = silu_f(v);
        *(__bf16*)(T1 + ((row * 256 + (nt * 16 + lr) * 2) ^ ((row & 7) << 4))) = (__bf16)v;
      }
    }
  }
  // GEMM2: [16 x 128] @ [128 x 128]
  f32x4 acc2[8];
#pragma unroll
  for (int nt = 0; nt < 8; ++nt) {
    const float bb = bm2[nt * 16 + lr];
#pragma unroll
    for (int r = 0; r < 4; ++r) acc2[nt][r] = bb;
  }
#pragma unroll
  for (int kt = 0; kt < 4; ++kt) {
    const bf16x8 a = *(const bf16x8*)(T1 + ((lr * 256 + kt * 64 + lg * 16) ^ ((lr & 7) << 4)));
#pragma unroll
    for (int nt = 0; nt < 8; ++nt) {
      const bf16x8 b = *(const bf16x8*)(W2L + ((kt * 8 + nt) * 64 + l) * 16);
      acc2[nt] = __builtin_amdgcn_mfma_f32_16x16x32_bf16(a, b, acc2[nt], 0, 0, 0);
    }
  }
  // LN2 + SiLU -> T1 (overwrite safe: all GEMM2 reads precede in program order)
  {
    float g2c[8], s2c[8];
#pragma unroll
    for (int nt = 0; nt < 8; ++nt) { g2c[nt] = gm2[nt * 16 + lr]; s2c[nt] = sm2[nt * 16 + lr]; }
#pragma unroll
    for (int r = 0; r < 4; ++r) {
      float s = 0.f, q = 0.f;
#pragma unroll
      for (int nt = 0; nt < 8; ++nt) { const float v = acc2[nt][r]; s += v; q += v * v; }
#pragma unroll
      for (int m = 1; m < 16; m <<= 1) { s += __shfl_xor(s, m); q += __shfl_xor(q, m); }
      const float mu = s * 0.0078125f;
      const float rstd = rsqrtf(q * 0.0078125f - mu * mu + 1e-5f);
      const int row = lg * 4 + r;
#pragma unroll
      for (int nt = 0; nt < 8; ++nt) {
        float v = (acc2[nt][r] - mu) * rstd * g2c[nt] + s2c[nt];
        v = silu_f(v);
        *(__bf16*)(T1 + ((row * 256 + (nt * 16 + lr) * 2) ^ ((row & 7) << 4))) = (__bf16)v;
      }
    }
  }
  // contiguous msg store: 16 edges x 256B = 4KB as 4 x 1KB wave stores
  char* mbase = (char*)(msg + (size_t)e0 * 128);
#pragma unroll
  for (int j = 0; j < 4; ++j) {
    const int row = j * 4 + lg;
    const uint4 v = *(const uint4*)(T1 + ((row * 256 + lr * 16) ^ ((row & 7) << 4)));
    *(uint4*)(mbase + j * 1024 + l * 16) = v;
  }
}

// ---------------------------------------------------------------------------
// CSR gather at FULL occupancy: wave handles one node (64 lanes x 2 dims),
// eord index is wave-uniform; msg row reads are coalesced 256B.
// Writes agg (fp32) once. grid = NN*64/256 blocks of 256.
// ---------------------------------------------------------------------------
__global__ void gather_kernel(const __bf16* __restrict__ msg,
                              const int* __restrict__ rowstart, const int* __restrict__ deg,
                              const int* __restrict__ eord, float* __restrict__ agg) {
  const int t = blockIdx.x * 256 + threadIdx.x;   // grid exactly NN*64/256
  const int n = t >> 6, pd = t & 63;              // pd covers dims 2*pd, 2*pd+1
  const int s = rowstart[n], dg = deg[n];
  float a0 = 0.f, a1 = 0.f;
  int i = 0;
  for (; i + 2 <= dg; i += 2) {
    const unsigned v0 = *(const unsigned*)(msg + (size_t)eord[s + i] * 128 + pd * 2);
    const unsigned v1 = *(const unsigned*)(msg + (size_t)eord[s + i + 1] * 128 + pd * 2);
    a0 += __uint_as_float(v0 << 16) + __uint_as_float(v1 << 16);
    a1 += __uint_as_float(v0 & 0xFFFF0000u) + __uint_as_float(v1 & 0xFFFF0000u);
  }
  if (i < dg) {
    const unsigned v0 = *(const unsigned*)(msg + (size_t)eord[s + i] * 128 + pd * 2);
    a0 += __uint_as_float(v0 << 16);
    a1 += __uint_as_float(v0 & 0xFFFF0000u);
  }
  f32x2 o; o[0] = a0; o[1] = a1;
  *(f32x2*)(agg + (size_t)n * 128 + pd * 2) = o;
}

// ---------------------------------------------------------------------------
// Node-update MLP (gather removed): 4 waves/block, 16 nodes/wave.
// ---------------------------------------------------------------------------
__global__ __launch_bounds__(256) void update_kernel(
    float* __restrict__ h, const float* __restrict__ aggv, __bf16* __restrict__ hbf,
    float* __restrict__ h0, const int mode,
    const __bf16* __restrict__ w1p, const __bf16* __restrict__ w2p,
    const float* __restrict__ bu1, const float* __restrict__ gu1, const float* __restrict__ su1,
    const float* __restrict__ bu2, const float* __restrict__ gu2, const float* __restrict__ su2) {
  __shared__ __bf16 T1s[4][16 * 128];   // 16 KB
  const int t = threadIdx.x, w = t >> 6, l = t & 63;
  const int lr = l & 15, lg = l >> 4;
  char* T1 = (char*)T1s[w];
  const int n0 = blockIdx.x * 64 + w * 16;
  const int n = n0 + lr;
  const int valid = (n < NN);
  const int nc = valid ? n : 0;

  // A fragments: kt 0..3 from hbf, kt 4..7 from agg (fp32 -> bf16)
  bf16x8 ah[4], af[4];
#pragma unroll
  for (int kt = 0; kt < 4; ++kt) {
    ah[kt] = *(const bf16x8*)(hbf + (size_t)nc * 128 + kt * 32 + lg * 8);
    const f32x4* pA = (const f32x4*)(aggv + (size_t)nc * 128 + kt * 32 + lg * 8);
    const f32x4 u0 = pA[0], u1 = pA[1];
#pragma unroll
    for (int j = 0; j < 4; ++j) {
      af[kt][j] = (__bf16)u0[j];
      af[kt][j + 4] = (__bf16)u1[j];
    }
  }
  // GEMM1: [16 x 256] @ [256 x 128]
  f32x4 acc[8];
#pragma unroll
  for (int nt = 0; nt < 8; ++nt) {
    const float bb = bu1[nt * 16 + lr];
#pragma unroll
    for (int r = 0; r < 4; ++r) acc[nt][r] = bb;
  }
#pragma unroll
  for (int kt = 0; kt < 8; ++kt) {
    const bf16x8 a = (kt < 4) ? ah[kt] : af[kt - 4];
#pragma unroll
    for (int nt = 0; nt < 8; ++nt) {
      const bf16x8 b = *(const bf16x8*)(w1p + ((size_t)((kt * 8 + nt) * 64 + l)) * 8);
      acc[nt] = __builtin_amdgcn_mfma_f32_16x16x32_bf16(a, b, acc[nt], 0, 0, 0);
    }
  }
  // LN1 + SiLU -> T1
  {
    float g1c[8], s1c[8];
#pragma unroll
    for (int nt = 0; nt < 8; ++nt) { g1c[nt] = gu1[nt * 16 + lr]; s1c[nt] = su1[nt * 16 + lr]; }
#pragma unroll
    for (int r = 0; r < 4; ++r) {
      float s = 0.f, q = 0.f;
#pragma unroll
      for (int nt = 0; nt < 8; ++nt) { const float v = acc[nt][r]; s += v; q += v * v; }
#pragma unroll
      for (int m = 1; m < 16; m <<= 1) { s += __shfl_xor(s, m); q += __shfl_xor(q, m); }
      const float mu = s * 0.0078125f;
      const float rstd = rsqrtf(q * 0.0078125f - mu * mu + 1e-5f);
      const int row = lg * 4 + r;
#pragma unroll
      for (int nt = 0; nt < 8; ++nt) {
        float v = (acc[nt][r] - mu) * rstd * g1c[nt] + s1c[nt];
        v = silu_f(v);
        const int col = nt * 16 + lr;
        *(__bf16*)(T1 + ((row * 256 + col * 2) ^ ((row & 7) << 4))) = (__bf16)v;
      }
    }
  }
  // GEMM2: [16 x 128] @ [128 x 128]
  f32x4 acc2[8];
#pragma unroll
  for (int nt = 0; nt < 8; ++nt) {
    const float bb = bu2[nt * 16 + lr];
#pragma unroll
    for (int r = 0; r < 4; ++r) acc2[nt][r] = bb;
  }
#pragma unroll
  for (int kt = 0; kt < 4; ++kt) {
    const bf16x8 a = *(const bf16x8*)(T1 + ((lr * 256 + kt * 64 + lg * 16) ^ ((lr & 7) << 4)));
#pragma unroll
    for (int nt = 0; nt < 8; ++nt) {
      const bf16x8 b = *(const bf16x8*)(w2p + ((size_t)((kt * 8 + nt) * 64 + l)) * 8);
      acc2[nt] = __builtin_amdgcn_mfma_f32_16x16x32_bf16(a, b, acc2[nt], 0, 0, 0);
    }
  }
  // LN2 + SiLU + store h/hbf (+ residual, h0)
  {
    float g2c[8], s2c[8];
#pragma unroll
    for (int nt = 0; nt < 8; ++nt) { g2c[nt] = gu2[nt * 16 + lr]; s2c[nt] = su2[nt * 16 + lr]; }
#pragma unroll
    for (int r = 0; r < 4; ++r) {
      float s = 0.f, q = 0.f;
#pragma unroll
      for (int nt = 0; nt < 8; ++nt) { const float v = acc2[nt][r]; s += v; q += v * v; }
#pragma unroll
      for (int m = 1; m < 16; m <<= 1) { s += __shfl_xor(s, m); q += __shfl_xor(q, m); }
      const float mu = s * 0.0078125f;
      const float rstd = rsqrtf(q * 0.0078125f - mu * mu + 1e-5f);
      const int row = lg * 4 + r;
      const int nn = n0 + row;
      if (nn < NN) {
#pragma unroll
        for (int nt = 0; nt < 8; ++nt) {
          const int col = nt * 16 + lr;
          float v = (acc2[nt][r] - mu) * rstd * g2c[nt] + s2c[nt];
          v = silu_f(v);
          if (mode) v += h0[(size_t)nn * 128 + col];
          h[(size_t)nn * 128 + col] = v;
          hbf[(size_t)nn * 128 + col] = (__bf16)v;
          if (mode) h0[(size_t)nn * 128 + col] = v;
        }
      }
    }
  }
}

// ---------------------------------------------------------------------------
// Segmented pool at proper parallelism: 32 nodes/block, register accumulate,
// one atomic flush per bid-change (~80K atomics total, 625 blocks).
// ---------------------------------------------------------------------------
__global__ void pool_kernel(const float* __restrict__ h, const int* __restrict__ bid,
                            float* __restrict__ pooled) {
  const int d = threadIdx.x;                 // 128 threads
  const int n0 = blockIdx.x * 32;
  const int nend = (n0 + 32 < NN) ? (n0 + 32) : NN;
  float acc = 0.f;
  int cur = bid[n0];
  for (int n = n0; n < nend; ++n) {
    const int b = bid[n];                    // uniform across block -> broadcast
    if (b != cur) { atomicAdd(&pooled[cur * 128 + d], acc); acc = 0.f; cur = b; }
    acc += h[(size_t)n * 128 + d];
  }
  atomicAdd(&pooled[cur * 128 + d], acc);
}

__global__ void head_kernel(const float* __restrict__ pooled,
                            const float* __restrict__ W1, const float* __restrict__ b1,
                            const float* __restrict__ W2, const float* __restrict__ b2,
                            float* __restrict__ out) {
  __shared__ float buf[2];
  const int b = blockIdx.x, t = threadIdx.x;
  float s = b1[t];
  for (int k = 0; k < 128; ++k) s += pooled[b * 128 + k] * W1[k * 128 + t];
  s = fmaxf(s, 0.f) * W2[t];
#pragma unroll
  for (int m = 32; m >= 1; m >>= 1) s += __shfl_down(s, m);
  if ((t & 63) == 0) buf[t >> 6] = s;
  __syncthreads();
  if (t == 0) out[b] = buf[0] + buf[1] + b2[0];
}

// ---------------------------------------------------------------------------
extern "C" void kernel_launch(void* const* d_in, const int* in_sizes, int n_in,
                              void* d_out, int out_size, void* d_ws, size_t ws_size,
                              hipStream_t stream) {
  const float* x   = (const float*)d_in[0];
  const float* pos = (const float*)d_in[1];
  const int* eis[4] = {(const int*)d_in[2], (const int*)d_in[3],
                       (const int*)d_in[4], (const int*)d_in[5]};
  const int* bid = (const int*)d_in[6];
  const float* embW = (const float*)d_in[7];
  const float* embB = (const float*)d_in[8];
  const float* Wm1 = (const float*)d_in[9];
  const float* bm1 = (const float*)d_in[10];
  const float* gm1 = (const float*)d_in[11];
  const float* sm1 = (const float*)d_in[12];
  const float* Wm2 = (const float*)d_in[13];
  const float* bm2 = (const float*)d_in[14];
  const float* gm2 = (const float*)d_in[15];
  const float* sm2 = (const float*)d_in[16];
  const float* Wu1 = (const float*)d_in[17];
  const float* bu1 = (const float*)d_in[18];
  const float* gu1 = (const float*)d_in[19];
  const float* su1 = (const float*)d_in[20];
  const float* Wu2 = (const float*)d_in[21];
  const float* bu2 = (const float*)d_in[22];
  const float* gu2 = (const float*)d_in[23];
  const float* su2 = (const float*)d_in[24];
  const float* pW1 = (const float*)d_in[25];
  const float* pb1 = (const float*)d_in[26];
  const float* pW2 = (const float*)d_in[27];
  const float* pb2 = (const float*)d_in[28];
  float* out = (float*)d_out;

  char* wp = (char*)d_ws;
  float* h = (float*)wp;      wp += (size_t)NN * 128 * 4;
  float* h0 = (float*)wp;     wp += (size_t)NN * 128 * 4;
  float* agg = (float*)wp;    wp += (size_t)NN * 128 * 4;
  float* pooled = (float*)wp; wp += 16 * 128 * 4;
  __bf16* hbf = (__bf16*)wp;  wp += (size_t)NN * 128 * 2;
  __bf16* msg = (__bf16*)wp;  wp += (size_t)NE * 128 * 2;   // 41 MB edge-order messages
  __bf16* w1p = (__bf16*)wp;  wp += (size_t)NL * 32768 * 2;
  __bf16* w2p = (__bf16*)wp;  wp += (size_t)NL * 16384 * 2;
  __bf16* wu1p = (__bf16*)wp; wp += (size_t)NL * 32768 * 2;
  __bf16* wu2p = (__bf16*)wp; wp += (size_t)NL * 16384 * 2;
  int* deg = (int*)wp;        wp += (size_t)4 * NN * 4;
  int* cursor = (int*)wp;     wp += (size_t)4 * NN * 4;
  int* rowstart = (int*)wp;   wp += (size_t)4 * NN * 4;
  int* eord = (int*)wp;       wp += (size_t)4 * NE * 4;

  // allow 160KB dynamic LDS for the edge kernel (host-side, capture-safe)
  static int lds_attr_set = 0;
  if (!lds_attr_set) {
    hipFuncSetAttribute((const void*)edge_msg_kernel,
                        hipFuncAttributeMaxDynamicSharedMemorySize, 163840);
    lds_attr_set = 1;
  }

  pack_weights<<<320, 256, 0, stream>>>(Wm1, w1p, 256, 257 * 128, NL * 8 * 8 * 64);
  pack_weights<<<160, 256, 0, stream>>>(Wm2, w2p, 128, 128 * 128, NL * 4 * 8 * 64);
  pack_weights<<<320, 256, 0, stream>>>(Wu1, wu1p, 256, 256 * 128, NL * 8 * 8 * 64);
  pack_weights<<<160, 256, 0, stream>>>(Wu2, wu2p, 128, 128 * 128, NL * 4 * 8 * 64);

  // CSR build (deg and cursor are adjacent -> one memset)
  hipMemsetAsync(deg, 0, (size_t)8 * NN * 4, stream);
  embed_kernel<<<(NN * 128) / 256, 256, 0, stream>>>(x, embW, embB, h, h0, hbf);
  for (int r = 0; r < 4; ++r)
    hist_kernel<<<NE / 256, 256, 0, stream>>>(eis[r], deg + (size_t)r * NN);
  scan_kernel<<<4, 1024, 0, stream>>>(deg, rowstart);
  for (int r = 0; r < 4; ++r)
    fill_kernel<<<NE / 256, 256, 0, stream>>>(eis[r], rowstart + (size_t)r * NN,
                                              cursor + (size_t)r * NN, eord + (size_t)r * NE);

  for (int layer = 0; layer < 5; ++layer) {
    for (int r = 0; r < 4; ++r) {
      const int i = layer * 4 + r;
      edge_msg_kernel<<<NE / 256, 1024, 163840, stream>>>(
          hbf, pos, eis[r], msg,
          w1p + (size_t)i * 32768, w2p + (size_t)i * 16384,
          Wm1 + (size_t)i * 257 * 128 + 256 * 128,
          bm1 + i * 128, gm1 + i * 128, sm1 + i * 128,
          bm2 + i * 128, gm2 + i * 128, sm2 + i * 128);
      gather_kernel<<<(NN * 64) / 256, 256, 0, stream>>>(
          msg, rowstart + (size_t)r * NN, deg + (size_t)r * NN, eord + (size_t)r * NE, agg);
      update_kernel<<<(NN + 63) / 64, 256, 0, stream>>>(
          h, agg, hbf, h0, (r == 3) ? 1 : 0,
          wu1p + (size_t)i * 32768, wu2p + (size_t)i * 16384,
          bu1 + i * 128, gu1 + i * 128, su1 + i * 128,
          bu2 + i * 128, gu2 + i * 128, su2 + i * 128);
    }
  }

  hipMemsetAsync(pooled, 0, 16 * 128 * 4, stream);
  pool_kernel<<<(NN + 31) / 32, 128, 0, stream>>>(h, bid, pooled);
  head_kernel<<<16, 128, 0, stream>>>(pooled, pW1, pb1, pW2, pb2, out);
}

// Round 7
// 1943.561 us; speedup vs baseline: 1.1526x; 1.0592x over previous
//
#include <hip/hip_runtime.h>

#define NN 20000      // nodes
#define NE 160000     // edges per edge set
#define NL 20         // EGNN layer calls (4*DEPTH)

typedef float f32x4 __attribute__((ext_vector_type(4)));
typedef float f32x2 __attribute__((ext_vector_type(2)));
typedef __bf16 bf16x8 __attribute__((ext_vector_type(8)));
typedef __bf16 bf16x4 __attribute__((ext_vector_type(4)));

__device__ __forceinline__ float silu_f(float v) {
  // fast: v * rcp(1+exp(-v)); v_rcp_f32 approx (~1ulp) is fine at bf16 output
  return v * __builtin_amdgcn_rcpf(1.f + __expf(-v));
}

// ---------------------------------------------------------------------------
// Pack fp32 weight matrix [L][K][128] into MFMA-fragment order (used as B or
// as A of the transposed product — same lane map on gfx950):
// out[((layer*ktn + kt)*8 + nt)*64 + lane][8], elem j = W[kt*32+(lane>>4)*8+j][nt*16+(lane&15)]
// ---------------------------------------------------------------------------
__global__ void pack_weights(const float* __restrict__ W, __bf16* __restrict__ out,
                             const int K, const int lstride, const int total) {
  const int idx = blockIdx.x * 256 + threadIdx.x;
  if (idx >= total) return;
  const int lane = idx & 63;
  const int nt = (idx >> 6) & 7;
  const int ktn = K >> 5;
  const int kt = (idx >> 9) % ktn;
  const int layer = (idx >> 9) / ktn;
  const int col = nt * 16 + (lane & 15);
  const int kb = kt * 32 + (lane >> 4) * 8;
  const float* src = W + (size_t)layer * lstride;
  __bf16* o = out + (size_t)idx * 8;
#pragma unroll
  for (int j = 0; j < 8; ++j) o[j] = (__bf16)src[(kb + j) * 128 + col];
}

// ---------------------------------------------------------------------------
// Pack Wm1 for the P/Q precompute: W'[k][c] (K=128, C=256) where
// c<128 -> Wm1[k][c] (P half), c>=128 -> Wm1[128+k][c-128] (Q half).
// Fragment order: out[((layer*4 + kt)*16 + nt)*64 + lane][8].
// ---------------------------------------------------------------------------
__global__ void pack_w1pq(const float* __restrict__ Wm1, __bf16* __restrict__ out) {
  const int idx = blockIdx.x * 256 + threadIdx.x;   // total = NL*4*16*64 = 81920
  const int lane = idx & 63;
  const int nt = (idx >> 6) & 15;
  const int kt = (idx >> 10) & 3;
  const int layer = idx >> 12;
  const int c = nt * 16 + (lane & 15);
  const int kb = kt * 32 + (lane >> 4) * 8;
  const float* src = Wm1 + (size_t)layer * 257 * 128;
  __bf16* o = out + (size_t)idx * 8;
#pragma unroll
  for (int j = 0; j < 8; ++j) {
    const int k = kb + j;
    o[j] = (__bf16)((c < 128) ? src[k * 128 + c] : src[(128 + k) * 128 + (c - 128)]);
  }
}

// ---------------------------------------------------------------------------
__global__ void embed_kernel(const float* __restrict__ x, const float* __restrict__ embW,
                             const float* __restrict__ embB,
                             float* __restrict__ h, float* __restrict__ h0,
                             __bf16* __restrict__ hbf) {
  const int idx = blockIdx.x * 256 + threadIdx.x;   // grid sized exactly NN*128/256
  const int n = idx >> 7, d = idx & 127;
  const float v = x[n] * embW[d] + embB[d];
  h[idx] = v;
  h0[idx] = v;
  hbf[idx] = (__bf16)v;
}

// ---------------------------------------------------------------------------
// CSR build: histogram of dst, exclusive scan, ordered edge list (eord).
// ---------------------------------------------------------------------------
__global__ void hist_kernel(const int* __restrict__ ei, int* __restrict__ deg) {
  const int e = blockIdx.x * 256 + threadIdx.x;   // grid exactly NE/256
  atomicAdd(&deg[ei[NE + e]], 1);
}

__global__ void scan_kernel(const int* __restrict__ deg, int* __restrict__ rowstart) {
  __shared__ int part[1024];
  const int r = blockIdx.x, t = threadIdx.x;
  const int* d = deg + (size_t)r * NN;
  int* rs = rowstart + (size_t)r * NN;
  int loc[20];
  int cnt = 0;
#pragma unroll
  for (int j = 0; j < 20; ++j) {
    const int i = t * 20 + j;
    const int v = (i < NN) ? d[i] : 0;
    loc[j] = cnt; cnt += v;
  }
  part[t] = cnt;
  __syncthreads();
  for (int off = 1; off < 1024; off <<= 1) {
    const int v = (t >= off) ? part[t - off] : 0;
    __syncthreads();
    part[t] += v;
    __syncthreads();
  }
  const int excl = (t == 0) ? 0 : part[t - 1];
#pragma unroll
  for (int j = 0; j < 20; ++j) {
    const int i = t * 20 + j;
    if (i < NN) rs[i] = excl + loc[j];
  }
}

__global__ void fill_kernel(const int* __restrict__ ei, const int* __restrict__ rowstart,
                            int* __restrict__ cursor, int* __restrict__ eord) {
  const int e = blockIdx.x * 256 + threadIdx.x;
  const int d = ei[NE + e];
  const int p = atomicAdd(&cursor[d], 1);
  eord[rowstart[d] + p] = e;
}

// ---------------------------------------------------------------------------
// P/Q precompute (transposed product): pq[n][0:128] = h@Wm1[:128,:],
// pq[n][128:256] = h@Wm1[128:256,:]. Wave = 16 nodes x 128 dims (half of 256);
// 2500 wave-tasks, exact. B-frag (h^T) gathered per lane; A-frag = pqw (L2).
// ---------------------------------------------------------------------------
__global__ __launch_bounds__(256) void pq_kernel(
    const __bf16* __restrict__ hbf, const __bf16* __restrict__ pqw,
    __bf16* __restrict__ pq) {
  __shared__ __bf16 T1s[4][2048];   // 4KB per wave
  const int t = threadIdx.x, w = t >> 6, l = t & 63;
  const int lr = l & 15, lg = l >> 4;
  const int wid = blockIdx.x * 4 + w;          // 0..2499
  const int n0 = (wid >> 1) * 16;
  const int half = wid & 1;
  char* T1 = (char*)T1s[w];

  const int node = n0 + lr;
  // B-fragments: h^T, lane holds h[node][ (lg*8 + 32kt) .. +8 )
  bf16x8 bq[4];
#pragma unroll
  for (int kt = 0; kt < 4; ++kt)
    bq[kt] = *(const bf16x8*)(hbf + (size_t)node * 128 + kt * 32 + lg * 8);

  f32x4 acc[8];
#pragma unroll
  for (int nt = 0; nt < 8; ++nt) acc[nt] = (f32x4)0.f;
#pragma unroll
  for (int kt = 0; kt < 4; ++kt) {
#pragma unroll
    for (int nt = 0; nt < 8; ++nt) {
      const bf16x8 a = *(const bf16x8*)(pqw + ((size_t)((kt * 16 + half * 8 + nt) * 64 + l)) * 8);
      acc[nt] = __builtin_amdgcn_mfma_f32_16x16x32_bf16(a, bq[kt], acc[nt], 0, 0, 0);
    }
  }
  // D[d = (half*8+nt)*16 + lg*4 + r][node = lr] -> T1 row=lr (256B = this half)
#pragma unroll
  for (int nt = 0; nt < 8; ++nt) {
    bf16x4 v;
#pragma unroll
    for (int r = 0; r < 4; ++r) v[r] = (__bf16)acc[nt][r];
    *(bf16x4*)(T1 + ((lr * 256 + nt * 32 + lg * 8) ^ ((lr & 7) << 4))) = v;
  }
  __builtin_amdgcn_s_waitcnt(0);  // lgkmcnt(0) for own-wave ds ops
  // wave store: 16 rows x 256B -> pq[node][half*128 ..]
#pragma unroll
  for (int j = 0; j < 4; ++j) {
    const int row = j * 4 + lg;
    const uint4 v = *(const uint4*)(T1 + ((row * 256 + lr * 16) ^ ((row & 7) << 4)));
    *(uint4*)(pq + (size_t)(n0 + row) * 256 + half * 128 + lr * 8) = v;
  }
}

// ---------------------------------------------------------------------------
// Edge-message kernel v3 (GEMM1 eliminated):
//   m1 = P[dst] + Q[src] + dist*w1last + bm1  (gather+add, fragment-ready)
//   -> LN1 -> SiLU -> GEMM2 as out^T = W2^T (LDS A) x m1^T (regs B)
//   -> LN2 -> SiLU -> T1 linearize -> contiguous msg stores.
// Block = 1024 thr (16 waves), LDS = 32KB W2 + 16x4KB T1 = 96KB.
// ---------------------------------------------------------------------------
__global__ __launch_bounds__(1024, 4) void edge_msg_kernel(
    const __bf16* __restrict__ pq, const float* __restrict__ pos,
    const int* __restrict__ ei, __bf16* __restrict__ msg,
    const __bf16* __restrict__ w2p, const float* __restrict__ w1last,
    const float* __restrict__ bm1, const float* __restrict__ gm1, const float* __restrict__ sm1,
    const float* __restrict__ bm2, const float* __restrict__ gm2, const float* __restrict__ sm2) {
  extern __shared__ char lds[];
  {
    const int t = threadIdx.x;
    uint4* d = (uint4*)lds;
    const uint4* s2 = (const uint4*)w2p;
    d[t] = s2[t];
    d[t + 1024] = s2[t + 1024];
  }
  __syncthreads();

  const int t = threadIdx.x, w = t >> 6, l = t & 63;
  const int lr = l & 15, lg = l >> 4;    // lr = edge-in-tile, lg = dim-chunk owner
  char* W2L = lds;                        // 32 KB
  char* T1  = lds + 32768 + w * 4096;     // 4 KB per wave

  const int e0 = blockIdx.x * 256 + w * 16;
  const int es = ei[e0 + lr], ed = ei[NE + e0 + lr];
  const float dx = pos[ed * 3 + 0] - pos[es * 3 + 0];
  const float dy = pos[ed * 3 + 1] - pos[es * 3 + 1];
  const float dz = pos[ed * 3 + 2] - pos[es * 3 + 2];
  const float dist = sqrtf(dx * dx + dy * dy + dz * dz);

  // m1 fp32, lane holds dims d = kt*32 + lg*8 + j  (fragment-ready for B)
  float v[4][8];
#pragma unroll
  for (int kt = 0; kt < 4; ++kt) {
    const int d0 = kt * 32 + lg * 8;
    const bf16x8 pA = *(const bf16x8*)(pq + (size_t)ed * 256 + d0);
    const bf16x8 qA = *(const bf16x8*)(pq + (size_t)es * 256 + 128 + d0);
    const f32x4 wl0 = *(const f32x4*)(w1last + d0), wl1 = *(const f32x4*)(w1last + d0 + 4);
    const f32x4 bb0 = *(const f32x4*)(bm1 + d0),    bb1 = *(const f32x4*)(bm1 + d0 + 4);
#pragma unroll
    for (int j = 0; j < 4; ++j) {
      v[kt][j]     = (float)pA[j]     + (float)qA[j]     + dist * wl0[j] + bb0[j];
      v[kt][j + 4] = (float)pA[j + 4] + (float)qA[j + 4] + dist * wl1[j] + bb1[j];
    }
  }
  // LN1: row = edge lr; 32 vals/lane, partners at lane^16, lane^32
  float s = 0.f, q = 0.f;
#pragma unroll
  for (int kt = 0; kt < 4; ++kt)
#pragma unroll
    for (int j = 0; j < 8; ++j) { const float x = v[kt][j]; s += x; q += x * x; }
  s += __shfl_xor(s, 16); q += __shfl_xor(q, 16);
  s += __shfl_xor(s, 32); q += __shfl_xor(q, 32);
  const float mu1 = s * 0.0078125f;
  const float rstd1 = rsqrtf(q * 0.0078125f - mu1 * mu1 + 1e-5f);
  // SiLU -> bf16 B-fragments
  bf16x8 bfrag[4];
#pragma unroll
  for (int kt = 0; kt < 4; ++kt) {
    const int d0 = kt * 32 + lg * 8;
    const f32x4 g0 = *(const f32x4*)(gm1 + d0), g1 = *(const f32x4*)(gm1 + d0 + 4);
    const f32x4 s0 = *(const f32x4*)(sm1 + d0), s1 = *(const f32x4*)(sm1 + d0 + 4);
    bf16x8 bf;
#pragma unroll
    for (int j = 0; j < 4; ++j) {
      bf[j]     = (__bf16)silu_f((v[kt][j]     - mu1) * rstd1 * g0[j] + s0[j]);
      bf[j + 4] = (__bf16)silu_f((v[kt][j + 4] - mu1) * rstd1 * g1[j] + s1[j]);
    }
    bfrag[kt] = bf;
  }
  // GEMM2 transposed: acc2[nt] = W2^T(tile nt) x m1^T ; D[d2][edge=lr]
  f32x4 acc2[8];
#pragma unroll
  for (int nt = 0; nt < 8; ++nt)
    acc2[nt] = *(const f32x4*)(bm2 + nt * 16 + lg * 4);
#pragma unroll
  for (int kt = 0; kt < 4; ++kt) {
#pragma unroll
    for (int nt = 0; nt < 8; ++nt) {
      const bf16x8 a = *(const bf16x8*)(W2L + ((kt * 8 + nt) * 64 + l) * 16);
      acc2[nt] = __builtin_amdgcn_mfma_f32_16x16x32_bf16(a, bfrag[kt], acc2[nt], 0, 0, 0);
    }
  }
  // LN2 over d2 for fixed edge lr: lane holds d2 = nt*16 + lg*4 + r
  float s2 = 0.f, q2 = 0.f;
#pragma unroll
  for (int nt = 0; nt < 8; ++nt)
#pragma unroll
    for (int r = 0; r < 4; ++r) { const float x = acc2[nt][r]; s2 += x; q2 += x * x; }
  s2 += __shfl_xor(s2, 16); q2 += __shfl_xor(q2, 16);
  s2 += __shfl_xor(s2, 32); q2 += __shfl_xor(q2, 32);
  const float mu2 = s2 * 0.0078125f;
  const float rstd2 = rsqrtf(q2 * 0.0078125f - mu2 * mu2 + 1e-5f);
  // SiLU -> T1 (row = edge lr, 256B), b64 packed writes
#pragma unroll
  for (int nt = 0; nt < 8; ++nt) {
    const f32x4 g2 = *(const f32x4*)(gm2 + nt * 16 + lg * 4);
    const f32x4 b2 = *(const f32x4*)(sm2 + nt * 16 + lg * 4);
    bf16x4 pk;
#pragma unroll
    for (int r = 0; r < 4; ++r)
      pk[r] = (__bf16)silu_f((acc2[nt][r] - mu2) * rstd2 * g2[r] + b2[r]);
    *(bf16x4*)(T1 + ((lr * 256 + nt * 32 + lg * 8) ^ ((lr & 7) << 4))) = pk;
  }
  __builtin_amdgcn_s_waitcnt(0);  // drain own-wave ds writes (wave-private T1)
  // contiguous msg store: 16 edges x 256B = 4 x 1KB wave stores
  char* mbase = (char*)(msg + (size_t)e0 * 128);
#pragma unroll
  for (int j = 0; j < 4; ++j) {
    const int row = j * 4 + lg;
    const uint4 val = *(const uint4*)(T1 + ((row * 256 + lr * 16) ^ ((row & 7) << 4)));
    *(uint4*)(mbase + j * 1024 + l * 16) = val;
  }
}

// ---------------------------------------------------------------------------
// CSR gather at full occupancy (unchanged from R6).
// ---------------------------------------------------------------------------
__global__ void gather_kernel(const __bf16* __restrict__ msg,
                              const int* __restrict__ rowstart, const int* __restrict__ deg,
                              const int* __restrict__ eord, float* __restrict__ agg) {
  const int t = blockIdx.x * 256 + threadIdx.x;   // grid exactly NN*64/256
  const int n = t >> 6, pd = t & 63;
  const int s = rowstart[n], dg = deg[n];
  float a0 = 0.f, a1 = 0.f;
  int i = 0;
  for (; i + 2 <= dg; i += 2) {
    const unsigned v0 = *(const unsigned*)(msg + (size_t)eord[s + i] * 128 + pd * 2);
    const unsigned v1 = *(const unsigned*)(msg + (size_t)eord[s + i + 1] * 128 + pd * 2);
    a0 += __uint_as_float(v0 << 16) + __uint_as_float(v1 << 16);
    a1 += __uint_as_float(v0 & 0xFFFF0000u) + __uint_as_float(v1 & 0xFFFF0000u);
  }
  if (i < dg) {
    const unsigned v0 = *(const unsigned*)(msg + (size_t)eord[s + i] * 128 + pd * 2);
    a0 += __uint_as_float(v0 << 16);
    a1 += __uint_as_float(v0 & 0xFFFF0000u);
  }
  f32x2 o; o[0] = a0; o[1] = a1;
  *(f32x2*)(agg + (size_t)n * 128 + pd * 2) = o;
}

// ---------------------------------------------------------------------------
// Node-update MLP (unchanged from R6).
// ---------------------------------------------------------------------------
__global__ __launch_bounds__(256) void update_kernel(
    float* __restrict__ h, const float* __restrict__ aggv, __bf16* __restrict__ hbf,
    float* __restrict__ h0, const int mode,
    const __bf16* __restrict__ w1p, const __bf16* __restrict__ w2p,
    const float* __restrict__ bu1, const float* __restrict__ gu1, const float* __restrict__ su1,
    const float* __restrict__ bu2, const float* __restrict__ gu2, const float* __restrict__ su2) {
  __shared__ __bf16 T1s[4][16 * 128];   // 16 KB
  const int t = threadIdx.x, w = t >> 6, l = t & 63;
  const int lr = l & 15, lg = l >> 4;
  char* T1 = (char*)T1s[w];
  const int n0 = blockIdx.x * 64 + w * 16;
  const int n = n0 + lr;
  const int valid = (n < NN);
  const int nc = valid ? n : 0;

  bf16x8 ah[4], af[4];
#pragma unroll
  for (int kt = 0; kt < 4; ++kt) {
    ah[kt] = *(const bf16x8*)(hbf + (size_t)nc * 128 + kt * 32 + lg * 8);
    const f32x4* pA = (const f32x4*)(aggv + (size_t)nc * 128 + kt * 32 + lg * 8);
    const f32x4 u0 = pA[0], u1 = pA[1];
#pragma unroll
    for (int j = 0; j < 4; ++j) {
      af[kt][j] = (__bf16)u0[j];
      af[kt][j + 4] = (__bf16)u1[j];
    }
  }
  f32x4 acc[8];
#pragma unroll
  for (int nt = 0; nt < 8; ++nt) {
    const float bb = bu1[nt * 16 + lr];
#pragma unroll
    for (int r = 0; r < 4; ++r) acc[nt][r] = bb;
  }
#pragma unroll
  for (int kt = 0; kt < 8; ++kt) {
    const bf16x8 a = (kt < 4) ? ah[kt] : af[kt - 4];
#pragma unroll
    for (int nt = 0; nt < 8; ++nt) {
      const bf16x8 b = *(const bf16x8*)(w1p + ((size_t)((kt * 8 + nt) * 64 + l)) * 8);
      acc[nt] = __builtin_amdgcn_mfma_f32_16x16x32_bf16(a, b, acc[nt], 0, 0, 0);
    }
  }
  {
    float g1c[8], s1c[8];
#pragma unroll
    for (int nt = 0; nt < 8; ++nt) { g1c[nt] = gu1[nt * 16 + lr]; s1c[nt] = su1[nt * 16 + lr]; }
#pragma unroll
    for (int r = 0; r < 4; ++r) {
      float s = 0.f, q = 0.f;
#pragma unroll
      for (int nt = 0; nt < 8; ++nt) { const float v = acc[nt][r]; s += v; q += v * v; }
#pragma unroll
      for (int m = 1; m < 16; m <<= 1) { s += __shfl_xor(s, m); q += __shfl_xor(q, m); }
      const float mu = s * 0.0078125f;
      const float rstd = rsqrtf(q * 0.0078125f - mu * mu + 1e-5f);
      const int row = lg * 4 + r;
#pragma unroll
      for (int nt = 0; nt < 8; ++nt) {
        float v = (acc[nt][r] - mu) * rstd * g1c[nt] + s1c[nt];
        v = silu_f(v);
        const int col = nt * 16 + lr;
        *(__bf16*)(T1 + ((row * 256 + col * 2) ^ ((row & 7) << 4))) = (__bf16)v;
      }
    }
  }
  __syncthreads();
  f32x4 acc2[8];
#pragma unroll
  for (int nt = 0; nt < 8; ++nt) {
    const float bb = bu2[nt * 16 + lr];
#pragma unroll
    for (int r = 0; r < 4; ++r) acc2[nt][r] = bb;
  }
#pragma unroll
  for (int kt = 0; kt < 4; ++kt) {
    const bf16x8 a = *(const bf16x8*)(T1 + ((lr * 256 + kt * 64 + lg * 16) ^ ((lr & 7) << 4)));
#pragma unroll
    for (int nt = 0; nt < 8; ++nt) {
      const bf16x8 b = *(const bf16x8*)(w2p + ((size_t)((kt * 8 + nt) * 64 + l)) * 8);
      acc2[nt] = __builtin_amdgcn_mfma_f32_16x16x32_bf16(a, b, acc2[nt], 0, 0, 0);
    }
  }
  {
    float g2c[8], s2c[8];
#pragma unroll
    for (int nt = 0; nt < 8; ++nt) { g2c[nt] = gu2[nt * 16 + lr]; s2c[nt] = su2[nt * 16 + lr]; }
#pragma unroll
    for (int r = 0; r < 4; ++r) {
      float s = 0.f, q = 0.f;
#pragma unroll
      for (int nt = 0; nt < 8; ++nt) { const float v = acc2[nt][r]; s += v; q += v * v; }
#pragma unroll
      for (int m = 1; m < 16; m <<= 1) { s += __shfl_xor(s, m); q += __shfl_xor(q, m); }
      const float mu = s * 0.0078125f;
      const float rstd = rsqrtf(q * 0.0078125f - mu * mu + 1e-5f);
      const int row = lg * 4 + r;
      const int nn = n0 + row;
      if (nn < NN) {
#pragma unroll
        for (int nt = 0; nt < 8; ++nt) {
          const int col = nt * 16 + lr;
          float v = (acc2[nt][r] - mu) * rstd * g2c[nt] + s2c[nt];
          v = silu_f(v);
          if (mode) v += h0[(size_t)nn * 128 + col];
          h[(size_t)nn * 128 + col] = v;
          hbf[(size_t)nn * 128 + col] = (__bf16)v;
          if (mode) h0[(size_t)nn * 128 + col] = v;
        }
      }
    }
  }
}

// ---------------------------------------------------------------------------
// Segmented pool (R6 version, 32 nodes/block).
// ---------------------------------------------------------------------------
__global__ void pool_kernel(const float* __restrict__ h, const int* __restrict__ bid,
                            float* __restrict__ pooled) {
  const int d = threadIdx.x;                 // 128 threads
  const int n0 = blockIdx.x * 32;
  const int nend = (n0 + 32 < NN) ? (n0 + 32) : NN;
  float acc = 0.f;
  int cur = bid[n0];
  for (int n = n0; n < nend; ++n) {
    const int b = bid[n];
    if (b != cur) { atomicAdd(&pooled[cur * 128 + d], acc); acc = 0.f; cur = b; }
    acc += h[(size_t)n * 128 + d];
  }
  atomicAdd(&pooled[cur * 128 + d], acc);
}

__global__ void head_kernel(const float* __restrict__ pooled,
                            const float* __restrict__ W1, const float* __restrict__ b1,
                            const float* __restrict__ W2, const float* __restrict__ b2,
                            float* __restrict__ out) {
  __shared__ float buf[2];
  const int b = blockIdx.x, t = threadIdx.x;
  float s = b1[t];
  for (int k = 0; k < 128; ++k) s += pooled[b * 128 + k] * W1[k * 128 + t];
  s = fmaxf(s, 0.f) * W2[t];
#pragma unroll
  for (int m = 32; m >= 1; m >>= 1) s += __shfl_down(s, m);
  if ((t & 63) == 0) buf[t >> 6] = s;
  __syncthreads();
  if (t == 0) out[b] = buf[0] + buf[1] + b2[0];
}

// ---------------------------------------------------------------------------
extern "C" void kernel_launch(void* const* d_in, const int* in_sizes, int n_in,
                              void* d_out, int out_size, void* d_ws, size_t ws_size,
                              hipStream_t stream) {
  const float* x   = (const float*)d_in[0];
  const float* pos = (const float*)d_in[1];
  const int* eis[4] = {(const int*)d_in[2], (const int*)d_in[3],
                       (const int*)d_in[4], (const int*)d_in[5]};
  const int* bid = (const int*)d_in[6];
  const float* embW = (const float*)d_in[7];
  const float* embB = (const float*)d_in[8];
  const float* Wm1 = (const float*)d_in[9];
  const float* bm1 = (const float*)d_in[10];
  const float* gm1 = (const float*)d_in[11];
  const float* sm1 = (const float*)d_in[12];
  const float* Wm2 = (const float*)d_in[13];
  const float* bm2 = (const float*)d_in[14];
  const float* gm2 = (const float*)d_in[15];
  const float* sm2 = (const float*)d_in[16];
  const float* Wu1 = (const float*)d_in[17];
  const float* bu1 = (const float*)d_in[18];
  const float* gu1 = (const float*)d_in[19];
  const float* su1 = (const float*)d_in[20];
  const float* Wu2 = (const float*)d_in[21];
  const float* bu2 = (const float*)d_in[22];
  const float* gu2 = (const float*)d_in[23];
  const float* su2 = (const float*)d_in[24];
  const float* pW1 = (const float*)d_in[25];
  const float* pb1 = (const float*)d_in[26];
  const float* pW2 = (const float*)d_in[27];
  const float* pb2 = (const float*)d_in[28];
  float* out = (float*)d_out;

  char* wp = (char*)d_ws;
  float* h = (float*)wp;      wp += (size_t)NN * 128 * 4;
  float* h0 = (float*)wp;     wp += (size_t)NN * 128 * 4;
  float* agg = (float*)wp;    wp += (size_t)NN * 128 * 4;
  float* pooled = (float*)wp; wp += 16 * 128 * 4;
  __bf16* hbf = (__bf16*)wp;  wp += (size_t)NN * 128 * 2;
  __bf16* pq = (__bf16*)wp;   wp += (size_t)NN * 256 * 2;   // 10.2 MB P|Q per layer
  __bf16* msg = (__bf16*)wp;  wp += (size_t)NE * 128 * 2;   // 41 MB edge-order messages
  __bf16* pqw = (__bf16*)wp;  wp += (size_t)NL * 32768 * 2; // Wm1 packed for P/Q
  __bf16* w2p = (__bf16*)wp;  wp += (size_t)NL * 16384 * 2;
  __bf16* wu1p = (__bf16*)wp; wp += (size_t)NL * 32768 * 2;
  __bf16* wu2p = (__bf16*)wp; wp += (size_t)NL * 16384 * 2;
  int* deg = (int*)wp;        wp += (size_t)4 * NN * 4;
  int* cursor = (int*)wp;     wp += (size_t)4 * NN * 4;
  int* rowstart = (int*)wp;   wp += (size_t)4 * NN * 4;
  int* eord = (int*)wp;       wp += (size_t)4 * NE * 4;

  static int lds_attr_set = 0;
  if (!lds_attr_set) {
    hipFuncSetAttribute((const void*)edge_msg_kernel,
                        hipFuncAttributeMaxDynamicSharedMemorySize, 98304);
    lds_attr_set = 1;
  }

  pack_w1pq<<<320, 256, 0, stream>>>(Wm1, pqw);
  pack_weights<<<160, 256, 0, stream>>>(Wm2, w2p, 128, 128 * 128, NL * 4 * 8 * 64);
  pack_weights<<<320, 256, 0, stream>>>(Wu1, wu1p, 256, 256 * 128, NL * 8 * 8 * 64);
  pack_weights<<<160, 256, 0, stream>>>(Wu2, wu2p, 128, 128 * 128, NL * 4 * 8 * 64);

  hipMemsetAsync(deg, 0, (size_t)8 * NN * 4, stream);
  embed_kernel<<<(NN * 128) / 256, 256, 0, stream>>>(x, embW, embB, h, h0, hbf);
  for (int r = 0; r < 4; ++r)
    hist_kernel<<<NE / 256, 256, 0, stream>>>(eis[r], deg + (size_t)r * NN);
  scan_kernel<<<4, 1024, 0, stream>>>(deg, rowstart);
  for (int r = 0; r < 4; ++r)
    fill_kernel<<<NE / 256, 256, 0, stream>>>(eis[r], rowstart + (size_t)r * NN,
                                              cursor + (size_t)r * NN, eord + (size_t)r * NE);

  for (int layer = 0; layer < 5; ++layer) {
    for (int r = 0; r < 4; ++r) {
      const int i = layer * 4 + r;
      pq_kernel<<<625, 256, 0, stream>>>(hbf, pqw + (size_t)i * 32768, pq);
      edge_msg_kernel<<<NE / 256, 1024, 98304, stream>>>(
          pq, pos, eis[r], msg,
          w2p + (size_t)i * 16384,
          Wm1 + (size_t)i * 257 * 128 + 256 * 128,
          bm1 + i * 128, gm1 + i * 128, sm1 + i * 128,
          bm2 + i * 128, gm2 + i * 128, sm2 + i * 128);
      gather_kernel<<<(NN * 64) / 256, 256, 0, stream>>>(
          msg, rowstart + (size_t)r * NN, deg + (size_t)r * NN, eord + (size_t)r * NE, agg);
      update_kernel<<<(NN + 63) / 64, 256, 0, stream>>>(
          h, agg, hbf, h0, (r == 3) ? 1 : 0,
          wu1p + (size_t)i * 32768, wu2p + (size_t)i * 16384,
          bu1 + i * 128, gu1 + i * 128, su1 + i * 128,
          bu2 + i * 128, gu2 + i * 128, su2 + i * 128);
    }
  }

  hipMemsetAsync(pooled, 0, 16 * 128 * 4, stream);
  pool_kernel<<<(NN + 31) / 32, 128, 0, stream>>>(h, bid, pooled);
  head_kernel<<<16, 128, 0, stream>>>(pooled, pW1, pb1, pW2, pb2, out);
}